// Round 1
// baseline (226.006 us; speedup 1.0000x reference)
//
#include <hip/hip_runtime.h>

#define K_NEIGH 32
#define D_FEAT  128

__device__ __forceinline__ float readlane_f(float v, int l) {
    return __int_as_float(__builtin_amdgcn_readlane(__float_as_int(v), l));
}

// One wave per batch element. Lane l owns dims {2l, 2l+1} (float2).
// Rows are STREAMED (not kept in registers): per pair (r, r+16) the o=32
// fold stage is applied at load time, so only 16+16 partial slots stay
// live. Selected rows are re-gathered (cache-warm) for the mean.
// Register footprint ~50-60 -> __launch_bounds__(256,6) for 6 waves/SIMD.
__global__ __launch_bounds__(256, 6) void intra_agg_kernel(
    const float* __restrict__ features,
    const int*   __restrict__ nodes,
    const int*   __restrict__ neighs,
    const int*   __restrict__ num_sample_p,
    float*       __restrict__ out,
    int batch)
{
    const int tid  = blockIdx.x * blockDim.x + threadIdx.x;
    const int lane = threadIdx.x & 63;
    int b = tid >> 6;
    if (b >= batch) return;
    b = __builtin_amdgcn_readfirstlane(b);   // force scalar index loads

    const int  ns = *num_sample_p;
    const int* nb = neighs + (size_t)b * K_NEIGH;

    // Center fragment (coalesced 512B across the wave).
    const int   cnode = nodes[b];
    const float2 c2 = ((const float2*)(features + (size_t)cnode * D_FEAT))[lane];

    // ||center|| via 6-step butterfly.
    float cc = c2.x * c2.x + c2.y * c2.y;
    #pragma unroll
    for (int m = 32; m >= 1; m >>= 1) cc += __shfl_xor(cc, m);
    const float cn = sqrtf(cc);

    const bool hi32 = (lane & 32) != 0;

    // Streaming pass: pair (r, r+16). Compute per-lane partials and apply
    // the o=32 fold immediately; after this, lanes 0-31 hold row r's
    // lane-pair sum in s[r]/t[r], lanes 32-63 hold row r+16's.
    float s[16], t[16];
    #pragma unroll
    for (int r = 0; r < 16; ++r) {
        const int ia = nb[r];                // wave-uniform -> s_load
        const int ib = nb[r + 16];
        const float2 va = ((const float2*)(features + (size_t)ia * D_FEAT))[lane];
        const float2 vb = ((const float2*)(features + (size_t)ib * D_FEAT))[lane];
        const float da  = c2.x * va.x + c2.y * va.y;
        const float db  = c2.x * vb.x + c2.y * vb.y;
        const float na  = va.x * va.x + va.y * va.y;
        const float nbq = vb.x * vb.x + vb.y * vb.y;
        const float sd = hi32 ? da : db;     // value sent across xor-32
        const float sn = hi32 ? na : nbq;
        const float rd = __shfl_xor(sd, 32);
        const float rn = __shfl_xor(sn, 32);
        s[r] = (hi32 ? db : da) + rd;        // kept + received
        t[r] = (hi32 ? nbq : na) + rn;
    }

    // Remaining fold stages (o = 16..2): identical to the verified fold.
    #pragma unroll
    for (int o = 16; o >= 2; o >>= 1) {
        const bool up = (lane & o) != 0;
        #pragma unroll
        for (int r = 0; r < o / 2; ++r) {
            const float sd = up ? s[r] : s[r + o / 2];
            const float sn = up ? t[r] : t[r + o / 2];
            const float rd = __shfl_xor(sd, o);
            const float rn = __shfl_xor(sn, o);
            const float kd = up ? s[r + o / 2] : s[r];
            const float kn = up ? t[r + o / 2] : t[r];
            s[r] = kd + rd;
            t[r] = kn + rn;
        }
    }
    s[0] += __shfl_xor(s[0], 1);
    t[0] += __shfl_xor(t[0], 1);

    const int   myrow = lane >> 1;           // row whose sim this lane holds
    const float sim   = s[0] / (cn * sqrtf(t[0]));

    // Stable rank (matches lax.top_k): readlane broadcasts, VALU only.
    int rank = 0;
    #pragma unroll
    for (int j = 0; j < K_NEIGH; ++j) {
        const float sj = readlane_f(sim, 2 * j);
        rank += (sj > sim || (sj == sim && j < myrow)) ? 1 : 0;
    }

    // Ballot has sel_r duplicated at bits 2r, 2r+1 -> compress even bits.
    const unsigned long long bal = __ballot(rank < ns);
    unsigned long long x = bal & 0x5555555555555555ull;
    x = (x | (x >> 1))  & 0x3333333333333333ull;
    x = (x | (x >> 2))  & 0x0F0F0F0F0F0F0F0Full;
    x = (x | (x >> 4))  & 0x00FF00FF00FF00FFull;
    x = (x | (x >> 8))  & 0x0000FFFF0000FFFFull;
    x = (x | (x >> 16)) & 0x00000000FFFFFFFFull;
    unsigned mask = (unsigned)x;             // bit r = row r selected
    mask = __builtin_amdgcn_readfirstlane(mask);  // provably wave-uniform

    // Re-gather only the ns selected rows (cache-warm) and average.
    float2 acc = make_float2(0.f, 0.f);
    unsigned m = mask;
    while (m) {
        const int r = __builtin_ctz(m); m &= m - 1;   // uniform scalar loop
        const int nidx = nb[r];
        const float2 v = ((const float2*)(features + (size_t)nidx * D_FEAT))[lane];
        acc.x += v.x; acc.y += v.y;
    }
    const float nsf = (float)ns;
    float2 ov;
    ov.x = fmaxf(acc.x / nsf, 0.f);
    ov.y = fmaxf(acc.y / nsf, 0.f);
    ((float2*)(out + (size_t)b * D_FEAT))[lane] = ov;
}

extern "C" void kernel_launch(void* const* d_in, const int* in_sizes, int n_in,
                              void* d_out, int out_size, void* d_ws, size_t ws_size,
                              hipStream_t stream) {
    const float* features = (const float*)d_in[0];
    const int*   nodes    = (const int*)d_in[1];
    const int*   neighs   = (const int*)d_in[2];
    const int*   ns       = (const int*)d_in[3];
    float*       out      = (float*)d_out;

    const int batch  = in_sizes[1];            // 32768
    const int blocks = (batch + 3) / 4;        // 4 waves per 256-thread block

    intra_agg_kernel<<<blocks, 256, 0, stream>>>(features, nodes, neighs, ns, out, batch);
}

// Round 2
// 154.741 us; speedup vs baseline: 1.4605x; 1.4605x over previous
//
#include <hip/hip_runtime.h>

#define K_NEIGH 32
#define D_FEAT  128

__device__ __forceinline__ float readlane_f(float v, int l) {
    return __int_as_float(__builtin_amdgcn_readlane(__float_as_int(v), l));
}

// One wave per batch element. Lane l owns dims {2l, 2l+1} (float2).
// Rows stay register-resident (each row read from HBM exactly once, mean
// comes from registers). Similarity fold stages o=32 AND o=16 are applied
// at load time (rows processed in quads q, q+8, q+16, q+24), so the live
// fold state is s[8]+t[8] instead of dt[32]+n2[32]. Live set ~100 VGPRs;
// permissive __launch_bounds__(256,4) (cap 128) -> no spills, 4-5 waves/SIMD.
__global__ __launch_bounds__(256, 4) void intra_agg_kernel(
    const float* __restrict__ features,
    const int*   __restrict__ nodes,
    const int*   __restrict__ neighs,
    const int*   __restrict__ num_sample_p,
    float*       __restrict__ out,
    int batch)
{
    const int tid  = blockIdx.x * blockDim.x + threadIdx.x;
    const int lane = threadIdx.x & 63;
    int b = tid >> 6;
    if (b >= batch) return;
    b = __builtin_amdgcn_readfirstlane(b);   // force scalar index loads

    const int  ns = *num_sample_p;
    const int* nb = neighs + (size_t)b * K_NEIGH;

    // Center fragment (coalesced 512B across the wave).
    const int   cnode = nodes[b];
    const float2 c2 = ((const float2*)(features + (size_t)cnode * D_FEAT))[lane];

    // ||center|| via 6-step butterfly.
    float cc = c2.x * c2.x + c2.y * c2.y;
    #pragma unroll
    for (int m = 32; m >= 1; m >>= 1) cc += __shfl_xor(cc, m);
    const float cn = sqrtf(cc);

    const bool hi32 = (lane & 32) != 0;
    const bool hi16 = (lane & 16) != 0;

    // Load all 32 rows into registers; fold o=32 and o=16 immediately.
    // pre16 slot q   <- rows (q,   q+16)   [o=32 fold]
    // pre16 slot q+8 <- rows (q+8, q+24)   [o=32 fold]
    // s[q] <- combine(slot q, slot q+8)    [o=16 fold]
    float2 rows[K_NEIGH];
    float s[8], t[8];
    #pragma unroll
    for (int q = 0; q < 8; ++q) {
        const int i0 = nb[q];                // wave-uniform -> s_load
        const int i1 = nb[q + 16];
        const int i2 = nb[q + 8];
        const int i3 = nb[q + 24];
        const float2 v0 = ((const float2*)(features + (size_t)i0 * D_FEAT))[lane];
        const float2 v1 = ((const float2*)(features + (size_t)i1 * D_FEAT))[lane];
        const float2 v2 = ((const float2*)(features + (size_t)i2 * D_FEAT))[lane];
        const float2 v3 = ((const float2*)(features + (size_t)i3 * D_FEAT))[lane];
        rows[q]      = v0;
        rows[q + 16] = v1;
        rows[q + 8]  = v2;
        rows[q + 24] = v3;

        const float d0 = c2.x*v0.x + c2.y*v0.y, n0 = v0.x*v0.x + v0.y*v0.y;
        const float d1 = c2.x*v1.x + c2.y*v1.y, n1 = v1.x*v1.x + v1.y*v1.y;
        const float d2 = c2.x*v2.x + c2.y*v2.y, n2 = v2.x*v2.x + v2.y*v2.y;
        const float d3 = c2.x*v3.x + c2.y*v3.y, n3 = v3.x*v3.x + v3.y*v3.y;

        // o=32 stage, pair (row q, row q+16) -> pre16 slot q
        float sd = hi32 ? d0 : d1;
        float sn = hi32 ? n0 : n1;
        float rd = __shfl_xor(sd, 32);
        float rn = __shfl_xor(sn, 32);
        const float sA = (hi32 ? d1 : d0) + rd;
        const float tA = (hi32 ? n1 : n0) + rn;

        // o=32 stage, pair (row q+8, row q+24) -> pre16 slot q+8
        sd = hi32 ? d2 : d3;
        sn = hi32 ? n2 : n3;
        rd = __shfl_xor(sd, 32);
        rn = __shfl_xor(sn, 32);
        const float sB = (hi32 ? d3 : d2) + rd;
        const float tB = (hi32 ? n3 : n2) + rn;

        // o=16 stage: sent = hi16 ? slot_q : slot_q8; kept = the other.
        const float sd2 = hi16 ? sA : sB;
        const float sn2 = hi16 ? tA : tB;
        const float rd2 = __shfl_xor(sd2, 16);
        const float rn2 = __shfl_xor(sn2, 16);
        s[q] = (hi16 ? sB : sA) + rd2;
        t[q] = (hi16 ? tB : tA) + rn2;
    }

    // Remaining fold stages (o = 8..2): identical body to the verified fold.
    #pragma unroll
    for (int o = 8; o >= 2; o >>= 1) {
        const bool up = (lane & o) != 0;
        #pragma unroll
        for (int r = 0; r < o / 2; ++r) {
            const float sd = up ? s[r] : s[r + o / 2];
            const float sn = up ? t[r] : t[r + o / 2];
            const float rd = __shfl_xor(sd, o);
            const float rn = __shfl_xor(sn, o);
            const float kd = up ? s[r + o / 2] : s[r];
            const float kn = up ? t[r + o / 2] : t[r];
            s[r] = kd + rd;
            t[r] = kn + rn;
        }
    }
    s[0] += __shfl_xor(s[0], 1);
    t[0] += __shfl_xor(t[0], 1);

    const int   myrow = lane >> 1;           // row whose sim this lane holds
    const float sim   = s[0] / (cn * sqrtf(t[0]));

    // Stable rank (matches lax.top_k): readlane broadcasts, VALU only.
    int rank = 0;
    #pragma unroll
    for (int j = 0; j < K_NEIGH; ++j) {
        const float sj = readlane_f(sim, 2 * j);
        rank += (sj > sim || (sj == sim && j < myrow)) ? 1 : 0;
    }

    // Ballot has sel_r duplicated at bits 2r, 2r+1 -> compress even bits.
    const unsigned long long bal = __ballot(rank < ns);
    unsigned long long x = bal & 0x5555555555555555ull;
    x = (x | (x >> 1))  & 0x3333333333333333ull;
    x = (x | (x >> 2))  & 0x0F0F0F0F0F0F0F0Full;
    x = (x | (x >> 4))  & 0x00FF00FF00FF00FFull;
    x = (x | (x >> 8))  & 0x0000FFFF0000FFFFull;
    x = (x | (x >> 16)) & 0x00000000FFFFFFFFull;
    const unsigned mask = (unsigned)x;       // bit r = row r selected

    // Mean over selected rows from registers: predicated FMA, zero loads.
    float2 acc = make_float2(0.f, 0.f);
    #pragma unroll
    for (int r = 0; r < K_NEIGH; ++r) {
        const float sel = (float)((mask >> r) & 1u);
        acc.x = fmaf(rows[r].x, sel, acc.x);
        acc.y = fmaf(rows[r].y, sel, acc.y);
    }
    const float nsf = (float)ns;
    float2 ov;
    ov.x = fmaxf(acc.x / nsf, 0.f);
    ov.y = fmaxf(acc.y / nsf, 0.f);
    ((float2*)(out + (size_t)b * D_FEAT))[lane] = ov;
}

extern "C" void kernel_launch(void* const* d_in, const int* in_sizes, int n_in,
                              void* d_out, int out_size, void* d_ws, size_t ws_size,
                              hipStream_t stream) {
    const float* features = (const float*)d_in[0];
    const int*   nodes    = (const int*)d_in[1];
    const int*   neighs   = (const int*)d_in[2];
    const int*   ns       = (const int*)d_in[3];
    float*       out      = (float*)d_out;

    const int batch  = in_sizes[1];            // 32768
    const int blocks = (batch + 3) / 4;        // 4 waves per 256-thread block

    intra_agg_kernel<<<blocks, 256, 0, stream>>>(features, nodes, neighs, ns, out, batch);
}